// Round 1
// baseline (354.495 us; speedup 1.0000x reference)
//
#include <hip/hip_runtime.h>

#define B_    8
#define S_    128
#define V_    200
#define W_    5
#define K_    80
#define ROT_  16
#define NPAIR 400            // W_ * K_
#define EPS_  1e-5f
#define TWO_PI_F 6.28318530717958647692f
#define STEP_F   0.39269908169872414f   // 2*pi/16
#define LOG2E_F  1.4426950408889634f

__device__ __forceinline__ float fast_exp2(float x) {
#if __has_builtin(__builtin_amdgcn_exp2f)
    return __builtin_amdgcn_exp2f(x);
#else
    return exp2f(x);
#endif
}

__global__ __launch_bounds__(NPAIR)
void lsresnet_gauss_conv(const float* __restrict__ feat,        // [B,S,V,W]
                         const float* __restrict__ rho_g,       // [B,S,V]
                         const float* __restrict__ theta_g,     // [B,S,V]
                         const float* __restrict__ mask_g,      // [B,S,V]
                         const float* __restrict__ mu_rho,      // [W*K]
                         const float* __restrict__ sigma_rho,   // [W*K]
                         const float* __restrict__ mu_theta,    // [W*K]
                         const float* __restrict__ sigma_theta, // [W*K]
                         const float* __restrict__ Wc,          // [W,K,K]
                         const float* __restrict__ bc,          // [W*K]
                         float* __restrict__ out)               // [B*S, W*K]
{
    // LDS layout (desc_s overlays th_s after the main loop):
    //   [0 .. 6400)        desc_s [NPAIR][ROT_]   (th_s uses [0..3200))
    //   [6400 .. 6600)     rho_s  [V_]
    //   [6600 .. 6800)     m_s    [V_]
    //   [6800 .. 7800)     mf_s   [V_][W_]
    __shared__ float lds[NPAIR * ROT_ + V_ + V_ + V_ * W_];
    float* th_s   = lds;
    float* desc_s = lds;
    float* rho_s  = lds + NPAIR * ROT_;
    float* m_s    = rho_s + V_;
    float* mf_s   = m_s + V_;

    const int bs  = blockIdx.x;          // patch index b*S + s
    const int tid = threadIdx.x;         // (w,kk) pair: tid = w*K_ + kk
    const int w   = tid / K_;
    const int o   = tid - w * K_;

    // ---- Phase A: stage per-vertex data into LDS -------------------------
    if (tid < V_) {
        const int v = tid;
        const size_t gi = (size_t)bs * V_ + v;
        const float rho = rho_g[gi];
        const float th  = theta_g[gi];
        const float m   = mask_g[gi];
        rho_s[v] = rho;
        m_s[v]   = m;
        #pragma unroll
        for (int r = 0; r < ROT_; ++r) {
            float t = th + (float)r * STEP_F;      // < 4*pi
            t = (t < TWO_PI_F) ? t : (t - TWO_PI_F);  // == mod(t, 2*pi)
            th_s[v * ROT_ + r] = t;
        }
        const float* fp = feat + gi * W_;
        #pragma unroll
        for (int ww = 0; ww < W_; ++ww)
            mf_s[v * W_ + ww] = m * fp[ww];
    }

    // Per-pair parameters (fold EPS and log2(e) into the exponent scales,
    // with the minus sign, so the inner body is sub/mul/fma/exp2).
    const float murho = mu_rho[tid];
    const float srho  = sigma_rho[tid];
    const float crho  = -LOG2E_F / (srho * srho + EPS_);
    const float muth  = mu_theta[tid];
    const float sth   = sigma_theta[tid];
    const float cth   = -LOG2E_F / (sth * sth + EPS_);

    __syncthreads();

    // ---- Phase B: accumulate sum(g) and sum(g*f) over vertices -----------
    float acc_g[ROT_], acc_gf[ROT_];
    #pragma unroll
    for (int r = 0; r < ROT_; ++r) { acc_g[r] = 0.f; acc_gf[r] = 0.f; }

    for (int v = 0; v < V_; ++v) {
        const float rho = rho_s[v];                 // broadcast
        const float m   = m_s[v];                   // broadcast
        const float mf  = mf_s[v * W_ + w];         // 5 distinct addrs
        const float d   = rho - murho;
        const float erho = d * d * crho;            // rho exponent (log2 dom)
        #pragma unroll
        for (int r = 0; r < ROT_; ++r) {
            const float dth = th_s[v * ROT_ + r] - muth;
            const float e   = fmaf(dth * dth, cth, erho);
            const float x   = fast_exp2(e);         // v_exp_f32
            acc_g[r]  = fmaf(x, m,  acc_g[r]);
            acc_gf[r] = fmaf(x, mf, acc_gf[r]);
        }
    }

    // ---- Phase C: normalize -> desc in LDS -------------------------------
    __syncthreads();   // all reads of th_s complete before overlay write
    #pragma unroll
    for (int r = 0; r < ROT_; ++r)
        desc_s[tid * ROT_ + r] = acc_gf[r] / (acc_g[r] + EPS_);
    __syncthreads();

    // ---- Phase D: conv (desc[w,:,r] . Wc[w,:,o]) + bias, max over rot ----
    float s[ROT_];
    #pragma unroll
    for (int r = 0; r < ROT_; ++r) s[r] = 0.f;

    const float* wcol = Wc + ((size_t)w * K_) * K_ + o;   // Wc[w, kk, o]
    const float* drow = desc_s + (size_t)w * K_ * ROT_;
    for (int kk = 0; kk < K_; ++kk) {
        const float wv = wcol[kk * K_];                   // coalesced over o
        #pragma unroll
        for (int r = 0; r < ROT_; ++r)
            s[r] = fmaf(drow[kk * ROT_ + r], wv, s[r]);   // broadcast reads
    }
    float best = s[0];
    #pragma unroll
    for (int r = 1; r < ROT_; ++r) best = fmaxf(best, s[r]);

    out[(size_t)bs * NPAIR + tid] = best + bc[tid];
}

extern "C" void kernel_launch(void* const* d_in, const int* in_sizes, int n_in,
                              void* d_out, int out_size, void* d_ws, size_t ws_size,
                              hipStream_t stream) {
    const float* feat        = (const float*)d_in[0];
    const float* rho         = (const float*)d_in[1];
    const float* theta       = (const float*)d_in[2];
    const float* mask        = (const float*)d_in[3];
    const float* mu_rho      = (const float*)d_in[4];
    const float* sigma_rho   = (const float*)d_in[5];
    const float* mu_theta    = (const float*)d_in[6];
    const float* sigma_theta = (const float*)d_in[7];
    const float* Wc          = (const float*)d_in[8];
    const float* bc          = (const float*)d_in[9];
    float* out = (float*)d_out;

    dim3 grid(B_ * S_);
    dim3 block(NPAIR);   // 400 threads = 6.25 waves; one (w,kk) pair per thread
    hipLaunchKernelGGL(lsresnet_gauss_conv, grid, block, 0, stream,
                       feat, rho, theta, mask,
                       mu_rho, sigma_rho, mu_theta, sigma_theta,
                       Wc, bc, out);
}